// Round 1
// 223.537 us; speedup vs baseline: 1.0091x; 1.0091x over previous
//
#include <hip/hip_runtime.h>
#include <hip/hip_bf16.h>
#include <hip/hip_fp16.h>
#include <math.h>

// Problem constants
#define BSZ 8
#define LSEQ 4096
#define HDIM 512
#define PDIM 256
#define MROWS (BSZ * LSEQ)        // 32768
#define NDIM 512                  // 2*PDIM
#define CHUNK 64
#define NCHUNK (LSEQ / CHUNK)     // 64

typedef __attribute__((ext_vector_type(8))) short bf16x8;
typedef __attribute__((ext_vector_type(4))) float f32x4;

// ---------------------------------------------------------------------------
// x (fp32) -> xb (bf16)
// ---------------------------------------------------------------------------
__global__ __launch_bounds__(256) void convert_x(const float* __restrict__ x,
                                                 __hip_bfloat16* __restrict__ xb,
                                                 int n4) {
    int i = blockIdx.x * blockDim.x + threadIdx.x;
    if (i >= n4) return;
    float4 v = ((const float4*)x)[i];
    union { ushort4 u; __hip_bfloat16 h[4]; } o;
    o.h[0] = __float2bfloat16(v.x);
    o.h[1] = __float2bfloat16(v.y);
    o.h[2] = __float2bfloat16(v.z);
    o.h[3] = __float2bfloat16(v.w);
    ((ushort4*)xb)[i] = o.u;
}

// ---------------------------------------------------------------------------
// W1T (bf16, N x K = 512 x 512): row 2p -> Re(B_bar[p][:]), row 2p+1 -> Im.
// Interleaved re/im so the scan gets half2-coalesced access.
// Double-precision transcendentals to match numpy ref. Emits Lambda_bar f32.
// ---------------------------------------------------------------------------
__global__ void precompute_w1(const float* __restrict__ Lre,
                              const float* __restrict__ Lim,
                              const float* __restrict__ logstep,
                              const float* __restrict__ Bmat,  // (P,H,2)
                              __hip_bfloat16* __restrict__ W1T,
                              float* __restrict__ a_re,
                              float* __restrict__ a_im) {
    int idx = blockIdx.x * blockDim.x + threadIdx.x;  // p*H + h
    if (idx >= PDIM * HDIM) return;
    int p = idx / HDIM, h = idx % HDIM;
    double step = exp((double)logstep[p]);
    double dlr = (double)Lre[p], dli = (double)Lim[p];
    double mag = exp(dlr * step);
    double ar = mag * cos(dli * step);
    double ai = mag * sin(dli * step);
    double den = dlr * dlr + dli * dli;
    double nr = ar - 1.0, ni = ai;
    double fr = (nr * dlr + ni * dli) / den;
    double fi = (ni * dlr - nr * dli) / den;
    double br = (double)Bmat[(size_t)(p * HDIM + h) * 2 + 0];
    double bi = (double)Bmat[(size_t)(p * HDIM + h) * 2 + 1];
    W1T[(size_t)(2 * p) * HDIM + h]     = __float2bfloat16((float)(fr * br - fi * bi));
    W1T[(size_t)(2 * p + 1) * HDIM + h] = __float2bfloat16((float)(fr * bi + fi * br));
    if (h == 0) { a_re[p] = (float)ar; a_im[p] = (float)ai; }
}

// W2T (bf16, N x K = 512 x 512): W2T[h][2p] = 2*C_re[h][p]; [h][2p+1] = -2*C_im[h][p]
__global__ void precompute_w2(const float* __restrict__ Cmat,  // (H,P,2)
                              __hip_bfloat16* __restrict__ W2T) {
    int idx = blockIdx.x * blockDim.x + threadIdx.x;  // h*P + p
    if (idx >= HDIM * PDIM) return;
    int h = idx / PDIM, p = idx % PDIM;
    float cr = Cmat[(size_t)(h * PDIM + p) * 2 + 0];
    float ci = Cmat[(size_t)(h * PDIM + p) * 2 + 1];
    W2T[(size_t)h * NDIM + 2 * p]     = __float2bfloat16(2.0f * cr);
    W2T[(size_t)h * NDIM + 2 * p + 1] = __float2bfloat16(-2.0f * ci);
}

// ---------------------------------------------------------------------------
// bf16 MFMA GEMM: C(MxN, OT) = A(MxK,bf16) @ BT(NxK,bf16)^T [+ D*xskip]
// m97-structure: 128x128 tile, BK=32, 256 threads = 4 waves (2x2), each wave
// owns a 64x64 quadrant = 4x4 frags of 16x16x32 (16 MFMA/wave/K-step).
// global_load_lds width-16 staging, 16 KB LDS, single-buffered 2-barrier loop.
// Grid: (M/128, N/128) with ROW tile as fast dim so the 4 blocks sharing an
// A panel get consecutive-mod-8-equal linear ids -> same XCD L2.
// ---------------------------------------------------------------------------
template <typename OT, bool SKIP>
__global__ __launch_bounds__(256) void gemm_bt(
    const __hip_bfloat16* __restrict__ A,   // M x K
    const __hip_bfloat16* __restrict__ BT,  // N x K
    OT* __restrict__ C,                     // M x N
    const float* __restrict__ Dvec,
    const __hip_bfloat16* __restrict__ Xskip,
    int M, int N, int K) {
    __shared__ __hip_bfloat16 smA[128 * 32];   // 8 KB
    __shared__ __hip_bfloat16 smB[128 * 32];   // 8 KB

    const int tid = threadIdx.x;
    const int lane = tid & 63;
    const int wave = tid >> 6;            // 0..3
    const int row0 = blockIdx.x * 128;    // row tile fast dim
    const int col0 = blockIdx.y * 128;
    const int wm = (wave >> 1) * 64;
    const int wn = (wave & 1) * 64;

    const int sr = lane >> 2;             // 0..15
    const int sk = (lane & 3) * 8;
    const int quad = lane >> 4;           // 0..3
    const int l15 = lane & 15;

    f32x4 acc[4][4] = {};

    for (int k0 = 0; k0 < K; k0 += 32) {
#pragma unroll
        for (int q = 0; q < 2; ++q) {     // A+B staging: 128 rows each, 2 issues/wave/mat
            const int chunk = wave * 32 + q * 16;
            const __hip_bfloat16* gA = A + (size_t)(row0 + chunk + sr) * K + k0 + sk;
            __builtin_amdgcn_global_load_lds(
                (const __attribute__((address_space(1))) void*)gA,
                (__attribute__((address_space(3))) void*)&smA[chunk * 32], 16, 0, 0);
            const __hip_bfloat16* gB = BT + (size_t)(col0 + chunk + sr) * K + k0 + sk;
            __builtin_amdgcn_global_load_lds(
                (const __attribute__((address_space(1))) void*)gB,
                (__attribute__((address_space(3))) void*)&smB[chunk * 32], 16, 0, 0);
        }
        __syncthreads();

        bf16x8 af[4], bfr[4];
#pragma unroll
        for (int i = 0; i < 4; ++i)
            af[i] = *(const bf16x8*)&smA[(wm + i * 16 + l15) * 32 + quad * 8];
#pragma unroll
        for (int j = 0; j < 4; ++j)
            bfr[j] = *(const bf16x8*)&smB[(wn + j * 16 + l15) * 32 + quad * 8];
#pragma unroll
        for (int i = 0; i < 4; ++i)
#pragma unroll
            for (int j = 0; j < 4; ++j)
                acc[i][j] = __builtin_amdgcn_mfma_f32_16x16x32_bf16(
                    af[i], bfr[j], acc[i][j], 0, 0, 0);
        __syncthreads();
    }

    // Epilogue: D row = quad*4 + r, col = l15 (m89/m91-verified layout)
#pragma unroll
    for (int i = 0; i < 4; ++i) {
        const int mbase = row0 + wm + i * 16 + quad * 4;
#pragma unroll
        for (int j = 0; j < 4; ++j) {
            const int col = col0 + wn + j * 16 + l15;
            const float dv = SKIP ? Dvec[col] : 0.0f;
#pragma unroll
            for (int r = 0; r < 4; ++r) {
                const size_t m = (size_t)(mbase + r);
                float v = acc[i][j][r];
                if (SKIP) v += dv * __bfloat162float(Xskip[m * N + col]);
                if constexpr (sizeof(OT) == 2) {
                    C[m * N + col] = OT(v);
                } else {
                    C[m * N + col] = v;
                }
            }
        }
    }
}

// ---------------------------------------------------------------------------
// Scan pass A: per (b, chunk), per-p thread: local scan from zero over CHUNK
// steps; write chunk-end state.  Bu fp16 interleaved: [m][2p]=re, [m][2p+1]=im.
// ---------------------------------------------------------------------------
__global__ __launch_bounds__(256) void scan_chunks(const __half2* __restrict__ Bu2,
                                                   const float* __restrict__ a_re,
                                                   const float* __restrict__ a_im,
                                                   float2* __restrict__ S) {
    int b = blockIdx.x / NCHUNK;
    int c = blockIdx.x % NCHUNK;
    int p = threadIdx.x;
    float ar = a_re[p], ai = a_im[p];
    float sr = 0.0f, si = 0.0f;
    size_t m0 = (size_t)b * LSEQ + (size_t)c * CHUNK;
    for (int j = 0; j < CHUNK; ++j) {
        float2 u = __half22float2(Bu2[(m0 + j) * PDIM + p]);
        float nsr = ar * sr - ai * si + u.x;
        float nsi = ar * si + ai * sr + u.y;
        sr = nsr; si = nsi;
    }
    S[(size_t)(b * NCHUNK + c) * PDIM + p] = make_float2(sr, si);
}

// Scan pass B: per (b,p): exclusive prefix over chunk states, decay a^CHUNK.
__global__ __launch_bounds__(256) void scan_carry(const float2* __restrict__ S,
                                                  const float* __restrict__ a_re,
                                                  const float* __restrict__ a_im,
                                                  float2* __restrict__ carry) {
    int b = blockIdx.x;
    int p = threadIdx.x;
    double ar = (double)a_re[p], ai = (double)a_im[p];
#pragma unroll
    for (int i = 0; i < 6; ++i) {
        double nr = ar * ar - ai * ai;
        double ni = 2.0 * ar * ai;
        ar = nr; ai = ni;
    }
    float alr = (float)ar, ali = (float)ai;
    float cr = 0.0f, ci = 0.0f;
    for (int c = 0; c < NCHUNK; ++c) {
        carry[(size_t)(b * NCHUNK + c) * PDIM + p] = make_float2(cr, ci);
        float2 s = S[(size_t)(b * NCHUNK + c) * PDIM + p];
        float ncr = alr * cr - ali * ci + s.x;
        float nci = alr * ci + ali * cr + s.y;
        cr = ncr; ci = nci;
    }
}

// Scan pass C: local scan seeded with carry; write xs as bf16 (interleaved).
__global__ __launch_bounds__(256) void scan_apply(const __half2* __restrict__ Bu2,
                                                  const float* __restrict__ a_re,
                                                  const float* __restrict__ a_im,
                                                  const float2* __restrict__ carry,
                                                  ushort2* __restrict__ xsb2) {
    int b = blockIdx.x / NCHUNK;
    int c = blockIdx.x % NCHUNK;
    int p = threadIdx.x;
    float ar = a_re[p], ai = a_im[p];
    float2 c0 = carry[(size_t)(b * NCHUNK + c) * PDIM + p];
    float sr = c0.x, si = c0.y;
    size_t m0 = (size_t)b * LSEQ + (size_t)c * CHUNK;
    for (int j = 0; j < CHUNK; ++j) {
        size_t idx = (m0 + j) * PDIM + p;
        float2 u = __half22float2(Bu2[idx]);
        float nsr = ar * sr - ai * si + u.x;
        float nsi = ar * si + ai * sr + u.y;
        sr = nsr; si = nsi;
        union { ushort2 u2; __hip_bfloat16 h[2]; } o;
        o.h[0] = __float2bfloat16(sr);
        o.h[1] = __float2bfloat16(si);
        xsb2[idx] = o.u2;
    }
}

// ---------------------------------------------------------------------------
extern "C" void kernel_launch(void* const* d_in, const int* in_sizes, int n_in,
                              void* d_out, int out_size, void* d_ws, size_t ws_size,
                              hipStream_t stream) {
    const float* x       = (const float*)d_in[0];
    const float* Lre     = (const float*)d_in[1];
    const float* Lim     = (const float*)d_in[2];
    const float* Bmat    = (const float*)d_in[3];
    const float* Cmat    = (const float*)d_in[4];
    const float* Dvec    = (const float*)d_in[5];
    const float* logstep = (const float*)d_in[6];
    float* out = (float*)d_out;

    char* ws = (char*)d_ws;
    const size_t MB = 1u << 20;
    __hip_bfloat16* xb  = (__hip_bfloat16*)(ws + 0);         // 32 MB
    __hip_bfloat16* xsb = (__hip_bfloat16*)(ws + 32 * MB);   // 32 MB
    __half* Bu          = (__half*)(ws + 64 * MB);           // 32 MB
    __hip_bfloat16* W1T = (__hip_bfloat16*)(ws + 96 * MB);   // 0.5 MB
    __hip_bfloat16* W2T = (__hip_bfloat16*)(ws + 96 * MB + 512 * 1024);
    float*  a_re  = (float*)(ws + 97 * MB);
    float*  a_im  = (float*)(ws + 97 * MB + 4096);
    float2* S     = (float2*)(ws + 98 * MB);                 // 1 MB
    float2* carry = (float2*)(ws + 99 * MB);                 // 1 MB

    // 1. Conversions / precompute
    convert_x<<<(MROWS * HDIM / 4 + 255) / 256, 256, 0, stream>>>(
        x, xb, MROWS * HDIM / 4);
    precompute_w1<<<(PDIM * HDIM + 255) / 256, 256, 0, stream>>>(
        Lre, Lim, logstep, Bmat, W1T, a_re, a_im);
    precompute_w2<<<(HDIM * PDIM + 255) / 256, 256, 0, stream>>>(Cmat, W2T);

    // 2. GEMM1: Bu(fp16) = xb @ W1T^T
    dim3 ggrid(MROWS / 128, NDIM / 128);  // (256, 4) = 1024 blocks, row-fast
    gemm_bt<__half, false><<<ggrid, 256, 0, stream>>>(
        xb, W1T, Bu, nullptr, nullptr, MROWS, NDIM, HDIM);

    // 3. Scan (3-pass chunked), emits xs as bf16
    scan_chunks<<<BSZ * NCHUNK, 256, 0, stream>>>((const __half2*)Bu, a_re, a_im, S);
    scan_carry<<<BSZ, 256, 0, stream>>>(S, a_re, a_im, carry);
    scan_apply<<<BSZ * NCHUNK, 256, 0, stream>>>((const __half2*)Bu, a_re, a_im,
                                                 carry, (ushort2*)xsb);

    // 4. GEMM2: out = xsb @ W2T^T + D*xb
    dim3 ggrid2(MROWS / 128, HDIM / 128);
    gemm_bt<float, true><<<ggrid2, 256, 0, stream>>>(
        xsb, W2T, out, Dvec, xb, MROWS, HDIM, NDIM);
}

// Round 2
// 219.735 us; speedup vs baseline: 1.0266x; 1.0173x over previous
//
#include <hip/hip_runtime.h>
#include <hip/hip_bf16.h>
#include <hip/hip_fp16.h>
#include <math.h>

// Problem constants
#define BSZ 8
#define LSEQ 4096
#define HDIM 512
#define PDIM 256
#define MROWS (BSZ * LSEQ)        // 32768
#define NDIM 512                  // 2*PDIM
#define CHUNK 64
#define NCHUNK (LSEQ / CHUNK)     // 64

typedef __attribute__((ext_vector_type(8))) short bf16x8;
typedef __attribute__((ext_vector_type(4))) float f32x4;

// ---------------------------------------------------------------------------
// x (fp32) -> xb (bf16)
// ---------------------------------------------------------------------------
__global__ __launch_bounds__(256) void convert_x(const float* __restrict__ x,
                                                 __hip_bfloat16* __restrict__ xb,
                                                 int n4) {
    int i = blockIdx.x * blockDim.x + threadIdx.x;
    if (i >= n4) return;
    float4 v = ((const float4*)x)[i];
    union { ushort4 u; __hip_bfloat16 h[4]; } o;
    o.h[0] = __float2bfloat16(v.x);
    o.h[1] = __float2bfloat16(v.y);
    o.h[2] = __float2bfloat16(v.z);
    o.h[3] = __float2bfloat16(v.w);
    ((ushort4*)xb)[i] = o.u;
}

// ---------------------------------------------------------------------------
// Per-p parameter kernel (256 threads, 1 block). Double-precision
// transcendentals ONCE per p (was 512x redundant per p). Emits:
//   f_re/f_im  : (Lambda_bar-1)/Lambda factor for B_bar
//   a_re/a_im  : Lambda_bar (f32)
//   al_re/al_im: Lambda_bar^CHUNK (computed in double, f32 out)
// ---------------------------------------------------------------------------
__global__ void precompute_params(const float* __restrict__ Lre,
                                  const float* __restrict__ Lim,
                                  const float* __restrict__ logstep,
                                  float* __restrict__ f_re, float* __restrict__ f_im,
                                  float* __restrict__ a_re, float* __restrict__ a_im,
                                  float* __restrict__ al_re, float* __restrict__ al_im) {
    int p = threadIdx.x;
    if (p >= PDIM) return;
    double step = exp((double)logstep[p]);
    double dlr = (double)Lre[p], dli = (double)Lim[p];
    double mag = exp(dlr * step);
    double ar = mag * cos(dli * step);
    double ai = mag * sin(dli * step);
    double den = dlr * dlr + dli * dli;
    double nr = ar - 1.0, ni = ai;
    f_re[p] = (float)((nr * dlr + ni * dli) / den);
    f_im[p] = (float)((ni * dlr - nr * dli) / den);
    a_re[p] = (float)ar;
    a_im[p] = (float)ai;
    double cr = ar, ci = ai;
#pragma unroll
    for (int i = 0; i < 6; ++i) {  // ^64
        double tr = cr * cr - ci * ci;
        double ti = 2.0 * cr * ci;
        cr = tr; ci = ti;
    }
    al_re[p] = (float)cr;
    al_im[p] = (float)ci;
}

// W1T (bf16, N x K = 512 x 512): row 2p -> Re(B_bar[p][:]), row 2p+1 -> Im.
__global__ __launch_bounds__(256) void precompute_w1(
    const float* __restrict__ f_re, const float* __restrict__ f_im,
    const float* __restrict__ Bmat,  // (P,H,2)
    __hip_bfloat16* __restrict__ W1T) {
    int idx = blockIdx.x * blockDim.x + threadIdx.x;  // p*H + h
    if (idx >= PDIM * HDIM) return;
    int p = idx / HDIM, h = idx % HDIM;
    float fr = f_re[p], fi = f_im[p];
    float br = Bmat[(size_t)(p * HDIM + h) * 2 + 0];
    float bi = Bmat[(size_t)(p * HDIM + h) * 2 + 1];
    W1T[(size_t)(2 * p) * HDIM + h]     = __float2bfloat16(fr * br - fi * bi);
    W1T[(size_t)(2 * p + 1) * HDIM + h] = __float2bfloat16(fr * bi + fi * br);
}

// W2T (bf16, N x K = 512 x 512): W2T[h][2p] = 2*C_re[h][p]; [h][2p+1] = -2*C_im[h][p]
__global__ void precompute_w2(const float* __restrict__ Cmat,  // (H,P,2)
                              __hip_bfloat16* __restrict__ W2T) {
    int idx = blockIdx.x * blockDim.x + threadIdx.x;  // h*P + p
    if (idx >= HDIM * PDIM) return;
    int h = idx / PDIM, p = idx % PDIM;
    float cr = Cmat[(size_t)(h * PDIM + p) * 2 + 0];
    float ci = Cmat[(size_t)(h * PDIM + p) * 2 + 1];
    W2T[(size_t)h * NDIM + 2 * p]     = __float2bfloat16(2.0f * cr);
    W2T[(size_t)h * NDIM + 2 * p + 1] = __float2bfloat16(-2.0f * ci);
}

// ---------------------------------------------------------------------------
// bf16 MFMA GEMM: C(MxN, OT) = A(MxK,bf16) @ BT(NxK,bf16)^T [+ D*xskip]
// 128x128 tile, BK=32, 4 waves (2x2), wave = 64x64 quadrant (4x4 frags).
// 2-PHASE double-buffered pipeline (T3-minimum): stage tile t+1 BEFORE
// computing tile t; ONE __syncthreads per K-step (its implicit vmcnt(0)
// drains loads that had the whole compute phase in flight).  LDS 32 KB.
// Grid row-fast so the 4 col-tile blocks sharing an A panel land on the
// same XCD (R1: FETCH 83->51 MB confirmed).
// ---------------------------------------------------------------------------
template <typename OT, bool SKIP>
__global__ __launch_bounds__(256) void gemm_bt(
    const __hip_bfloat16* __restrict__ A,   // M x K
    const __hip_bfloat16* __restrict__ BT,  // N x K
    OT* __restrict__ C,                     // M x N
    const float* __restrict__ Dvec,
    const __hip_bfloat16* __restrict__ Xskip,
    int M, int N, int K) {
    __shared__ __hip_bfloat16 smA[2 * 128 * 32];   // 16 KB
    __shared__ __hip_bfloat16 smB[2 * 128 * 32];   // 16 KB

    const int tid = threadIdx.x;
    const int lane = tid & 63;
    const int wave = tid >> 6;            // 0..3
    const int row0 = blockIdx.x * 128;    // row tile fast dim
    const int col0 = blockIdx.y * 128;
    const int wm = (wave >> 1) * 64;
    const int wn = (wave & 1) * 64;

    const int sr = lane >> 2;             // 0..15
    const int sk = (lane & 3) * 8;
    const int quad = lane >> 4;           // 0..3
    const int l15 = lane & 15;

    f32x4 acc[4][4] = {};

    auto stage = [&](int buf, int k0) {
#pragma unroll
        for (int q = 0; q < 2; ++q) {
            const int chunk = wave * 32 + q * 16;
            const __hip_bfloat16* gA = A + (size_t)(row0 + chunk + sr) * K + k0 + sk;
            __builtin_amdgcn_global_load_lds(
                (const __attribute__((address_space(1))) void*)gA,
                (__attribute__((address_space(3))) void*)&smA[buf * 4096 + chunk * 32],
                16, 0, 0);
            const __hip_bfloat16* gB = BT + (size_t)(col0 + chunk + sr) * K + k0 + sk;
            __builtin_amdgcn_global_load_lds(
                (const __attribute__((address_space(1))) void*)gB,
                (__attribute__((address_space(3))) void*)&smB[buf * 4096 + chunk * 32],
                16, 0, 0);
        }
    };

    const int nk = K >> 5;
    stage(0, 0);
    __syncthreads();          // implicit vmcnt(0): tile 0 resident
    int cur = 0;
    for (int t = 0; t < nk; ++t) {
        if (t + 1 < nk) stage(cur ^ 1, (t + 1) << 5);   // issue early

        const __hip_bfloat16* sA = &smA[cur * 4096];
        const __hip_bfloat16* sB = &smB[cur * 4096];
        bf16x8 af[4], bfr[4];
#pragma unroll
        for (int i = 0; i < 4; ++i)
            af[i] = *(const bf16x8*)&sA[(wm + i * 16 + l15) * 32 + quad * 8];
#pragma unroll
        for (int j = 0; j < 4; ++j)
            bfr[j] = *(const bf16x8*)&sB[(wn + j * 16 + l15) * 32 + quad * 8];
#pragma unroll
        for (int i = 0; i < 4; ++i)
#pragma unroll
            for (int j = 0; j < 4; ++j)
                acc[i][j] = __builtin_amdgcn_mfma_f32_16x16x32_bf16(
                    af[i], bfr[j], acc[i][j], 0, 0, 0);

        __syncthreads();      // drain late: loads had full compute phase
        cur ^= 1;
    }

    // Epilogue: D row = quad*4 + r, col = l15 (m89/m91-verified layout)
#pragma unroll
    for (int i = 0; i < 4; ++i) {
        const int mbase = row0 + wm + i * 16 + quad * 4;
#pragma unroll
        for (int j = 0; j < 4; ++j) {
            const int col = col0 + wn + j * 16 + l15;
            const float dv = SKIP ? Dvec[col] : 0.0f;
#pragma unroll
            for (int r = 0; r < 4; ++r) {
                const size_t m = (size_t)(mbase + r);
                float v = acc[i][j][r];
                if (SKIP) v += dv * __bfloat162float(Xskip[m * N + col]);
                if constexpr (sizeof(OT) == 2) {
                    C[m * N + col] = OT(v);
                } else {
                    C[m * N + col] = v;
                }
            }
        }
    }
}

// ---------------------------------------------------------------------------
// Scan pass A: per (b, chunk), per-p thread: local scan from zero over CHUNK
// steps; write chunk-end state.  Bu fp16 interleaved: [m][2p]=re, [m][2p+1]=im.
// ---------------------------------------------------------------------------
__global__ __launch_bounds__(256) void scan_chunks(const __half2* __restrict__ Bu2,
                                                   const float* __restrict__ a_re,
                                                   const float* __restrict__ a_im,
                                                   float2* __restrict__ S) {
    int b = blockIdx.x / NCHUNK;
    int c = blockIdx.x % NCHUNK;
    int p = threadIdx.x;
    float ar = a_re[p], ai = a_im[p];
    float sr = 0.0f, si = 0.0f;
    size_t m0 = (size_t)b * LSEQ + (size_t)c * CHUNK;
    for (int j = 0; j < CHUNK; ++j) {
        float2 u = __half22float2(Bu2[(m0 + j) * PDIM + p]);
        float nsr = ar * sr - ai * si + u.x;
        float nsi = ar * si + ai * sr + u.y;
        sr = nsr; si = nsi;
    }
    S[(size_t)(b * NCHUNK + c) * PDIM + p] = make_float2(sr, si);
}

// ---------------------------------------------------------------------------
// Scan pass B: WAVE-PARALLEL chunk-carry scan.  One wave per (b,p); lane =
// chunk index.  Hillis-Steele inclusive scan over the affine pairs
// (A=a^CHUNK, b=S_c) with the associative_scan operator, 6 shuffle steps.
// Replaces the 64-step serial loop on 8 blocks (~10 us latency-bound).
// ---------------------------------------------------------------------------
__global__ __launch_bounds__(256) void scan_carry(const float2* __restrict__ S,
                                                  const float* __restrict__ al_re,
                                                  const float* __restrict__ al_im,
                                                  float2* __restrict__ carry) {
    const int wid = blockIdx.x * 4 + (threadIdx.x >> 6);  // 0..2047
    const int b = wid >> 8;        // 0..7
    const int p = wid & 255;       // 0..255
    const int c = threadIdx.x & 63;  // lane = chunk
    float Ar = al_re[p], Ai = al_im[p];
    float2 s = S[(size_t)(b * NCHUNK + c) * PDIM + p];
    float br = s.x, bi = s.y;
#pragma unroll
    for (int d = 1; d < 64; d <<= 1) {
        float pAr = __shfl_up(Ar, d);
        float pAi = __shfl_up(Ai, d);
        float pbr = __shfl_up(br, d);
        float pbi = __shfl_up(bi, d);
        if (c >= d) {
            // (A_i,b_i)=prev (earlier), (A_j,b_j)=self: A=A_j*A_i, b=A_j*b_i+b_j
            float nAr = Ar * pAr - Ai * pAi;
            float nAi = Ar * pAi + Ai * pAr;
            float nbr = Ar * pbr - Ai * pbi + br;
            float nbi = Ar * pbi + Ai * pbr + bi;
            Ar = nAr; Ai = nAi; br = nbr; bi = nbi;
        }
    }
    // carry for chunk c = inclusive state through chunk c-1 (0 for c=0)
    float er = __shfl_up(br, 1);
    float ei = __shfl_up(bi, 1);
    if (c == 0) { er = 0.0f; ei = 0.0f; }
    carry[(size_t)(b * NCHUNK + c) * PDIM + p] = make_float2(er, ei);
}

// Scan pass C: local scan seeded with carry; write xs as bf16 (interleaved).
__global__ __launch_bounds__(256) void scan_apply(const __half2* __restrict__ Bu2,
                                                  const float* __restrict__ a_re,
                                                  const float* __restrict__ a_im,
                                                  const float2* __restrict__ carry,
                                                  ushort2* __restrict__ xsb2) {
    int b = blockIdx.x / NCHUNK;
    int c = blockIdx.x % NCHUNK;
    int p = threadIdx.x;
    float ar = a_re[p], ai = a_im[p];
    float2 c0 = carry[(size_t)(b * NCHUNK + c) * PDIM + p];
    float sr = c0.x, si = c0.y;
    size_t m0 = (size_t)b * LSEQ + (size_t)c * CHUNK;
    for (int j = 0; j < CHUNK; ++j) {
        size_t idx = (m0 + j) * PDIM + p;
        float2 u = __half22float2(Bu2[idx]);
        float nsr = ar * sr - ai * si + u.x;
        float nsi = ar * si + ai * sr + u.y;
        sr = nsr; si = nsi;
        union { ushort2 u2; __hip_bfloat16 h[2]; } o;
        o.h[0] = __float2bfloat16(sr);
        o.h[1] = __float2bfloat16(si);
        xsb2[idx] = o.u2;
    }
}

// ---------------------------------------------------------------------------
extern "C" void kernel_launch(void* const* d_in, const int* in_sizes, int n_in,
                              void* d_out, int out_size, void* d_ws, size_t ws_size,
                              hipStream_t stream) {
    const float* x       = (const float*)d_in[0];
    const float* Lre     = (const float*)d_in[1];
    const float* Lim     = (const float*)d_in[2];
    const float* Bmat    = (const float*)d_in[3];
    const float* Cmat    = (const float*)d_in[4];
    const float* Dvec    = (const float*)d_in[5];
    const float* logstep = (const float*)d_in[6];
    float* out = (float*)d_out;

    char* ws = (char*)d_ws;
    const size_t MB = 1u << 20;
    __hip_bfloat16* xb  = (__hip_bfloat16*)(ws + 0);         // 32 MB
    __hip_bfloat16* xsb = (__hip_bfloat16*)(ws + 32 * MB);   // 32 MB
    __half* Bu          = (__half*)(ws + 64 * MB);           // 32 MB
    __hip_bfloat16* W1T = (__hip_bfloat16*)(ws + 96 * MB);   // 0.5 MB
    __hip_bfloat16* W2T = (__hip_bfloat16*)(ws + 96 * MB + 512 * 1024);
    float*  a_re  = (float*)(ws + 97 * MB);
    float*  a_im  = (float*)(ws + 97 * MB + 4096);
    float*  f_re  = (float*)(ws + 97 * MB + 8192);
    float*  f_im  = (float*)(ws + 97 * MB + 12288);
    float*  al_re = (float*)(ws + 97 * MB + 16384);
    float*  al_im = (float*)(ws + 97 * MB + 20480);
    float2* S     = (float2*)(ws + 98 * MB);                 // 1 MB
    float2* carry = (float2*)(ws + 99 * MB);                 // 1 MB

    // 1. Conversions / precompute
    convert_x<<<(MROWS * HDIM / 4 + 255) / 256, 256, 0, stream>>>(
        x, xb, MROWS * HDIM / 4);
    precompute_params<<<1, 256, 0, stream>>>(Lre, Lim, logstep,
                                             f_re, f_im, a_re, a_im, al_re, al_im);
    precompute_w1<<<(PDIM * HDIM + 255) / 256, 256, 0, stream>>>(
        f_re, f_im, Bmat, W1T);
    precompute_w2<<<(HDIM * PDIM + 255) / 256, 256, 0, stream>>>(Cmat, W2T);

    // 2. GEMM1: Bu(fp16) = xb @ W1T^T
    dim3 ggrid(MROWS / 128, NDIM / 128);  // (256, 4) = 1024 blocks, row-fast
    gemm_bt<__half, false><<<ggrid, 256, 0, stream>>>(
        xb, W1T, Bu, nullptr, nullptr, MROWS, NDIM, HDIM);

    // 3. Scan (3-pass chunked), emits xs as bf16
    scan_chunks<<<BSZ * NCHUNK, 256, 0, stream>>>((const __half2*)Bu, a_re, a_im, S);
    scan_carry<<<BSZ * PDIM / 4, 256, 0, stream>>>(S, al_re, al_im, carry);
    scan_apply<<<BSZ * NCHUNK, 256, 0, stream>>>((const __half2*)Bu, a_re, a_im,
                                                 carry, (ushort2*)xsb);

    // 4. GEMM2: out = xsb @ W2T^T + D*xb
    dim3 ggrid2(MROWS / 128, HDIM / 128);
    gemm_bt<float, true><<<ggrid2, 256, 0, stream>>>(
        xsb, W2T, out, Dvec, xb, MROWS, HDIM, NDIM);
}

// Round 4
// 217.573 us; speedup vs baseline: 1.0368x; 1.0099x over previous
//
#include <hip/hip_runtime.h>
#include <hip/hip_bf16.h>
#include <hip/hip_fp16.h>
#include <math.h>

// Problem constants
#define BSZ 8
#define LSEQ 4096
#define HDIM 512
#define PDIM 256
#define MROWS (BSZ * LSEQ)        // 32768
#define NDIM 512                  // 2*PDIM
#define CHUNK 32
#define NCHUNK (LSEQ / CHUNK)     // 128
#define LOG2CHUNK 5

typedef __attribute__((ext_vector_type(8))) short bf16x8;
typedef __attribute__((ext_vector_type(4))) float f32x4;

// ---------------------------------------------------------------------------
// Per-p parameter kernel (256 threads, 1 block). Double-precision
// transcendentals ONCE per p. Emits f (B_bar factor), a=Lambda_bar,
// al=Lambda_bar^CHUNK.
// ---------------------------------------------------------------------------
__global__ void precompute_params(const float* __restrict__ Lre,
                                  const float* __restrict__ Lim,
                                  const float* __restrict__ logstep,
                                  float* __restrict__ f_re, float* __restrict__ f_im,
                                  float* __restrict__ a_re, float* __restrict__ a_im,
                                  float* __restrict__ al_re, float* __restrict__ al_im) {
    int p = threadIdx.x;
    if (p >= PDIM) return;
    double step = exp((double)logstep[p]);
    double dlr = (double)Lre[p], dli = (double)Lim[p];
    double mag = exp(dlr * step);
    double ar = mag * cos(dli * step);
    double ai = mag * sin(dli * step);
    double den = dlr * dlr + dli * dli;
    double nr = ar - 1.0, ni = ai;
    f_re[p] = (float)((nr * dlr + ni * dli) / den);
    f_im[p] = (float)((ni * dlr - nr * dli) / den);
    a_re[p] = (float)ar;
    a_im[p] = (float)ai;
    double cr = ar, ci = ai;
#pragma unroll
    for (int i = 0; i < LOG2CHUNK; ++i) {  // ^CHUNK
        double tr = cr * cr - ci * ci;
        double ti = 2.0 * cr * ci;
        cr = tr; ci = ti;
    }
    al_re[p] = (float)cr;
    al_im[p] = (float)ci;
}

// ---------------------------------------------------------------------------
// Merged prep kernel: convert_x (blocks [0, NCONV)), W1T (next 512 blocks),
// W2T (next 512).  Uniform branch per block; saves 2 kernel launches.
// ---------------------------------------------------------------------------
#define NCONV (MROWS * HDIM / 4 / 256)   // 16384
__global__ __launch_bounds__(256) void prep(
    const float* __restrict__ x, __hip_bfloat16* __restrict__ xb,
    const float* __restrict__ f_re, const float* __restrict__ f_im,
    const float* __restrict__ Bmat, __hip_bfloat16* __restrict__ W1T,
    const float* __restrict__ Cmat, __hip_bfloat16* __restrict__ W2T) {
    const int bid = blockIdx.x;
    const int tid = threadIdx.x;
    if (bid < NCONV) {
        int i = bid * 256 + tid;
        float4 v = ((const float4*)x)[i];
        union { ushort4 u; __hip_bfloat16 h[4]; } o;
        o.h[0] = __float2bfloat16(v.x);
        o.h[1] = __float2bfloat16(v.y);
        o.h[2] = __float2bfloat16(v.z);
        o.h[3] = __float2bfloat16(v.w);
        ((ushort4*)xb)[i] = o.u;
    } else if (bid < NCONV + 512) {
        int idx = (bid - NCONV) * 256 + tid;   // p*H + h
        int p = idx / HDIM, h = idx % HDIM;
        float fr = f_re[p], fi = f_im[p];
        float br = Bmat[(size_t)(p * HDIM + h) * 2 + 0];
        float bi = Bmat[(size_t)(p * HDIM + h) * 2 + 1];
        W1T[(size_t)(2 * p) * HDIM + h]     = __float2bfloat16(fr * br - fi * bi);
        W1T[(size_t)(2 * p + 1) * HDIM + h] = __float2bfloat16(fr * bi + fi * br);
    } else {
        int idx = (bid - NCONV - 512) * 256 + tid;  // h*P + p
        int h = idx / PDIM, p = idx % PDIM;
        float cr = Cmat[(size_t)(h * PDIM + p) * 2 + 0];
        float ci = Cmat[(size_t)(h * PDIM + p) * 2 + 1];
        W2T[(size_t)h * NDIM + 2 * p]     = __float2bfloat16(2.0f * cr);
        W2T[(size_t)h * NDIM + 2 * p + 1] = __float2bfloat16(-2.0f * ci);
    }
}

// ---------------------------------------------------------------------------
// bf16 MFMA GEMM: C(MxN, OT) = A(MxK,bf16) @ BT(NxK,bf16)^T [+ D*xskip]
// 128x128 tile, BK=32, 4 waves (2x2), wave = 64x64 quadrant (4x4 frags).
// 3-BUFFER COUNTED-VMCNT PIPELINE (T4): stage tile t+2 before computing
// tile t; s_waitcnt vmcnt(4) + raw s_barrier keeps tile t+2's 4 loads in
// flight ACROSS the barrier (never drain to 0 in the main loop).
// LDS XOR-swizzle (T2, both-sides per rule #21): global source k-segment
// pre-swizzled (linear DMA dest), ds_read applies the same XOR -> the
// 8-way bank conflict of row-major [128][32] drops to 2-way (free).
// Grid row-fast: 4 col-tile blocks sharing an A panel -> same XCD L2.
// ---------------------------------------------------------------------------
template <typename OT, bool SKIP>
__global__ __launch_bounds__(256) void gemm_bt(
    const __hip_bfloat16* __restrict__ A,   // M x K
    const __hip_bfloat16* __restrict__ BT,  // N x K
    OT* __restrict__ C,                     // M x N
    const float* __restrict__ Dvec,
    const __hip_bfloat16* __restrict__ Xskip,
    int M, int N, int K) {
    __shared__ __hip_bfloat16 smA[3 * 128 * 32];   // 24 KB
    __shared__ __hip_bfloat16 smB[3 * 128 * 32];   // 24 KB

    const int tid = threadIdx.x;
    const int lane = tid & 63;
    const int wave = tid >> 6;            // 0..3
    const int row0 = blockIdx.x * 128;    // row tile fast dim
    const int col0 = blockIdx.y * 128;
    const int wm = (wave >> 1) * 64;
    const int wn = (wave & 1) * 64;

    const int sr = lane >> 2;             // staged row within 16-row chunk
    // T2 swizzle: sw(row) = (row&3) ^ ((row>>2)&3); per-lane constants.
    const int swz_st = ((lane >> 2) & 3) ^ ((lane >> 4) & 3);   // sw of staged row
    const int sk = (((lane & 3) ^ swz_st) * 8);                 // swizzled k-seg (elems)
    const int quad = lane >> 4;           // 0..3
    const int l15 = lane & 15;
    const int rq = ((quad ^ ((l15 & 3) ^ ((l15 >> 2) & 3))) * 8);  // swizzled read seg

    f32x4 acc[4][4] = {};

    auto stage = [&](int buf, int t) {
        const int k0 = t << 5;
#pragma unroll
        for (int q = 0; q < 2; ++q) {
            const int chunk = wave * 32 + q * 16;
            const __hip_bfloat16* gA = A + (size_t)(row0 + chunk + sr) * K + k0 + sk;
            __builtin_amdgcn_global_load_lds(
                (const __attribute__((address_space(1))) void*)gA,
                (__attribute__((address_space(3))) void*)&smA[buf * 4096 + chunk * 32],
                16, 0, 0);
            const __hip_bfloat16* gB = BT + (size_t)(col0 + chunk + sr) * K + k0 + sk;
            __builtin_amdgcn_global_load_lds(
                (const __attribute__((address_space(1))) void*)gB,
                (__attribute__((address_space(3))) void*)&smB[buf * 4096 + chunk * 32],
                16, 0, 0);
        }
    };

    const int nk = K >> 5;
    stage(0, 0);
    stage(1, 1);
    asm volatile("s_waitcnt vmcnt(4)" ::: "memory");   // tile 0 resident, tile 1 flying
    __builtin_amdgcn_s_barrier();

    int cur = 0;
    for (int t = 0; t < nk; ++t) {
        if (t + 2 < nk) {
            int st = cur + 2; if (st >= 3) st -= 3;
            stage(st, t + 2);                          // issue BEFORE compute
        }

        const __hip_bfloat16* sA = &smA[cur * 4096];
        const __hip_bfloat16* sB = &smB[cur * 4096];
        bf16x8 af[4], bfr[4];
#pragma unroll
        for (int i = 0; i < 4; ++i)
            af[i] = *(const bf16x8*)&sA[(wm + i * 16 + l15) * 32 + rq];
#pragma unroll
        for (int j = 0; j < 4; ++j)
            bfr[j] = *(const bf16x8*)&sB[(wn + j * 16 + l15) * 32 + rq];
#pragma unroll
        for (int i = 0; i < 4; ++i)
#pragma unroll
            for (int j = 0; j < 4; ++j)
                acc[i][j] = __builtin_amdgcn_mfma_f32_16x16x32_bf16(
                    af[i], bfr[j], acc[i][j], 0, 0, 0);

        if (t + 1 < nk) {
            if (t + 2 < nk)
                asm volatile("s_waitcnt vmcnt(4)" ::: "memory");  // t+1 done, t+2 flying
            else
                asm volatile("s_waitcnt vmcnt(0)" ::: "memory");  // tail drain
            __builtin_amdgcn_s_barrier();
        }
        cur += 1; if (cur == 3) cur = 0;
    }

    // Epilogue: D row = quad*4 + r, col = l15 (m89/m91-verified layout)
#pragma unroll
    for (int i = 0; i < 4; ++i) {
        const int mbase = row0 + wm + i * 16 + quad * 4;
#pragma unroll
        for (int j = 0; j < 4; ++j) {
            const int col = col0 + wn + j * 16 + l15;
            const float dv = SKIP ? Dvec[col] : 0.0f;
#pragma unroll
            for (int r = 0; r < 4; ++r) {
                const size_t m = (size_t)(mbase + r);
                float v = acc[i][j][r];
                if (SKIP) v += dv * __bfloat162float(Xskip[m * N + col]);
                if constexpr (sizeof(OT) == 2) {
                    C[m * N + col] = OT(v);
                } else {
                    C[m * N + col] = v;
                }
            }
        }
    }
}

// ---------------------------------------------------------------------------
// Scan pass A: per (b, chunk), per-p thread: local scan from zero over CHUNK
// steps; write chunk-end state.  CHUNK=32 -> 1024 blocks (4/CU).
// ---------------------------------------------------------------------------
__global__ __launch_bounds__(256) void scan_chunks(const __half2* __restrict__ Bu2,
                                                   const float* __restrict__ a_re,
                                                   const float* __restrict__ a_im,
                                                   float2* __restrict__ S) {
    int b = blockIdx.x / NCHUNK;
    int c = blockIdx.x % NCHUNK;
    int p = threadIdx.x;
    float ar = a_re[p], ai = a_im[p];
    float sr = 0.0f, si = 0.0f;
    size_t m0 = (size_t)b * LSEQ + (size_t)c * CHUNK;
    for (int j = 0; j < CHUNK; ++j) {
        float2 u = __half22float2(Bu2[(m0 + j) * PDIM + p]);
        float nsr = ar * sr - ai * si + u.x;
        float nsi = ar * si + ai * sr + u.y;
        sr = nsr; si = nsi;
    }
    S[(size_t)(b * NCHUNK + c) * PDIM + p] = make_float2(sr, si);
}

// ---------------------------------------------------------------------------
// Scan pass B: wave-parallel chunk-carry scan over NCHUNK=128 chunks.
// One wave per (b,p); lane handles chunks 2*lane, 2*lane+1: serial pair
// combine, 6-step Hillis-Steele over pairs, then redistribute.
// ---------------------------------------------------------------------------
__global__ __launch_bounds__(256) void scan_carry(const float2* __restrict__ S,
                                                  const float* __restrict__ al_re,
                                                  const float* __restrict__ al_im,
                                                  float2* __restrict__ carry) {
    const int wid = blockIdx.x * 4 + (threadIdx.x >> 6);  // 0..2047
    const int b = wid >> 8;        // 0..7
    const int p = wid & 255;       // 0..255
    const int lane = threadIdx.x & 63;
    const int c0 = 2 * lane, c1 = 2 * lane + 1;
    float alr = al_re[p], ali = al_im[p];
    float2 s0 = S[(size_t)(b * NCHUNK + c0) * PDIM + p];
    float2 s1 = S[(size_t)(b * NCHUNK + c1) * PDIM + p];
    // pair combine (earlier=c0, later=c1): A = al^2, b = al*s0 + s1
    float Ar = alr * alr - ali * ali;
    float Ai = 2.0f * alr * ali;
    float br = alr * s0.x - ali * s0.y + s1.x;
    float bi = alr * s0.y + ali * s0.x + s1.y;
#pragma unroll
    for (int d = 1; d < 64; d <<= 1) {
        float pAr = __shfl_up(Ar, d);
        float pAi = __shfl_up(Ai, d);
        float pbr = __shfl_up(br, d);
        float pbi = __shfl_up(bi, d);
        if (lane >= d) {
            float nAr = Ar * pAr - Ai * pAi;
            float nAi = Ar * pAi + Ai * pAr;
            float nbr = Ar * pbr - Ai * pbi + br;
            float nbi = Ar * pbi + Ai * pbr + bi;
            Ar = nAr; Ai = nAi; br = nbr; bi = nbi;
        }
    }
    // exclusive state through pair lane-1 = carry for chunk c0
    float er = __shfl_up(br, 1);
    float ei = __shfl_up(bi, 1);
    if (lane == 0) { er = 0.0f; ei = 0.0f; }
    carry[(size_t)(b * NCHUNK + c0) * PDIM + p] = make_float2(er, ei);
    // carry for c1 = al*carry(c0) + s0
    carry[(size_t)(b * NCHUNK + c1) * PDIM + p] =
        make_float2(alr * er - ali * ei + s0.x, alr * ei + ali * er + s0.y);
}

// Scan pass C: local scan seeded with carry; write xs as bf16 (interleaved).
__global__ __launch_bounds__(256) void scan_apply(const __half2* __restrict__ Bu2,
                                                  const float* __restrict__ a_re,
                                                  const float* __restrict__ a_im,
                                                  const float2* __restrict__ carry,
                                                  ushort2* __restrict__ xsb2) {
    int b = blockIdx.x / NCHUNK;
    int c = blockIdx.x % NCHUNK;
    int p = threadIdx.x;
    float ar = a_re[p], ai = a_im[p];
    float2 c0 = carry[(size_t)(b * NCHUNK + c) * PDIM + p];
    float sr = c0.x, si = c0.y;
    size_t m0 = (size_t)b * LSEQ + (size_t)c * CHUNK;
    for (int j = 0; j < CHUNK; ++j) {
        size_t idx = (m0 + j) * PDIM + p;
        float2 u = __half22float2(Bu2[idx]);
        float nsr = ar * sr - ai * si + u.x;
        float nsi = ar * si + ai * sr + u.y;
        sr = nsr; si = nsi;
        union { ushort2 u2; __hip_bfloat16 h[2]; } o;
        o.h[0] = __float2bfloat16(sr);
        o.h[1] = __float2bfloat16(si);
        xsb2[idx] = o.u2;
    }
}

// ---------------------------------------------------------------------------
extern "C" void kernel_launch(void* const* d_in, const int* in_sizes, int n_in,
                              void* d_out, int out_size, void* d_ws, size_t ws_size,
                              hipStream_t stream) {
    const float* x       = (const float*)d_in[0];
    const float* Lre     = (const float*)d_in[1];
    const float* Lim     = (const float*)d_in[2];
    const float* Bmat    = (const float*)d_in[3];
    const float* Cmat    = (const float*)d_in[4];
    const float* Dvec    = (const float*)d_in[5];
    const float* logstep = (const float*)d_in[6];
    float* out = (float*)d_out;

    char* ws = (char*)d_ws;
    const size_t MB = 1u << 20;
    __hip_bfloat16* xb  = (__hip_bfloat16*)(ws + 0);         // 32 MB
    __hip_bfloat16* xsb = (__hip_bfloat16*)(ws + 32 * MB);   // 32 MB
    __half* Bu          = (__half*)(ws + 64 * MB);           // 32 MB
    __hip_bfloat16* W1T = (__hip_bfloat16*)(ws + 96 * MB);   // 0.5 MB
    __hip_bfloat16* W2T = (__hip_bfloat16*)(ws + 96 * MB + 512 * 1024);
    float*  a_re  = (float*)(ws + 97 * MB);
    float*  a_im  = (float*)(ws + 97 * MB + 4096);
    float*  f_re  = (float*)(ws + 97 * MB + 8192);
    float*  f_im  = (float*)(ws + 97 * MB + 12288);
    float*  al_re = (float*)(ws + 97 * MB + 16384);
    float*  al_im = (float*)(ws + 97 * MB + 20480);
    float2* S     = (float2*)(ws + 98 * MB);                 // 2 MB
    float2* carry = (float2*)(ws + 100 * MB);                // 2 MB

    // 1. Params (1 block), then merged prep (convert + W1 + W2)
    precompute_params<<<1, 256, 0, stream>>>(Lre, Lim, logstep,
                                             f_re, f_im, a_re, a_im, al_re, al_im);
    prep<<<NCONV + 1024, 256, 0, stream>>>(x, xb, f_re, f_im, Bmat, W1T, Cmat, W2T);

    // 2. GEMM1: Bu(fp16) = xb @ W1T^T
    dim3 ggrid(MROWS / 128, NDIM / 128);  // (256, 4) = 1024 blocks, row-fast
    gemm_bt<__half, false><<<ggrid, 256, 0, stream>>>(
        xb, W1T, Bu, nullptr, nullptr, MROWS, NDIM, HDIM);

    // 3. Scan (3-pass chunked), emits xs as bf16
    scan_chunks<<<BSZ * NCHUNK, 256, 0, stream>>>((const __half2*)Bu, a_re, a_im, S);
    scan_carry<<<BSZ * PDIM / 4, 256, 0, stream>>>(S, al_re, al_im, carry);
    scan_apply<<<BSZ * NCHUNK, 256, 0, stream>>>((const __half2*)Bu, a_re, a_im,
                                                 carry, (ushort2*)xsb);

    // 4. GEMM2: out = xsb @ W2T^T + D*xb
    dim3 ggrid2(MROWS / 128, HDIM / 128);
    gemm_bt<float, true><<<ggrid2, 256, 0, stream>>>(
        xsb, W2T, out, Dvec, xb, MROWS, HDIM, NDIM);
}